// Round 1
// baseline (1781.942 us; speedup 1.0000x reference)
//
#include <hip/hip_runtime.h>
#include <math.h>

#define BATCH 4096
#define HDIM  1024
#define KDIM0 7150
#define NACT  47
#define NA2   94
#define NEGC  -1000000000.0f

// output layout (floats): logits [0,385024), logp [385024,393216),
// actions [393216,401408), value [401408,405504)
#define LP_OFF  385024
#define ACT_OFF 393216
#define VAL_OFF 401408

// ---------------------------------------------------------------------------
// Generic split-K fp32 GEMM: C += A[M,K] @ W[K,N]  (atomicAdd epilogue).
// 128x128 tile, BK=16, 256 threads, TM=TN=8 (two 4-wide fragments at stride
// 64 so compute-phase LDS reads are <=2-way bank aliased = free).
// Bias is NOT applied here (folded into ln_relu / head).
// ---------------------------------------------------------------------------
__global__ __launch_bounds__(256, 4) void gemm_splitk_kernel(
    const float* __restrict__ A, const float* __restrict__ W,
    float* __restrict__ C, int M, int N, int K, int ksplit)
{
  __shared__ float As[16][132];
  __shared__ float Ws[16][132];
  const int t    = threadIdx.x;
  const int n0   = blockIdx.x * 128;
  const int m0   = blockIdx.y * 128;
  const int kbeg = blockIdx.z * ksplit;
  const int kend = min(K, kbeg + ksplit);
  const int tx = t & 15;
  const int ty = t >> 4;
  const int ar = t >> 1;          // A-stage row 0..127
  const int ak = (t & 1) * 8;     // A-stage k offset 0/8
  const int wr = t >> 4;          // W-stage k row 0..15
  const int wc = (t & 15) * 4;    // W-stage col 0..60

  float acc[8][8];
#pragma unroll
  for (int i = 0; i < 8; ++i)
#pragma unroll
    for (int j = 0; j < 8; ++j) acc[i][j] = 0.f;

  const float* Abase = A + (size_t)(m0 + ar) * K + ak;
  const float* Wbase = W + n0;

  for (int k0 = kbeg; k0 < kend; k0 += 16) {
    // stage A tile (128 x 16) transposed -> As[k][m]; K guard (K is even,
    // kend even, so float2 pairs never straddle the boundary)
#pragma unroll
    for (int j = 0; j < 8; j += 2) {
      float2 v = make_float2(0.f, 0.f);
      if (k0 + ak + j < kend) v = *(const float2*)(Abase + k0 + j);
      As[ak + j][ar]     = v.x;
      As[ak + j + 1][ar] = v.y;
    }
    // stage W tile (16 x 128) -> Ws[k][n], two float4 at stride 64
    {
      const float* wp = Wbase + (size_t)(k0 + wr) * N;
      float4 w0 = make_float4(0.f, 0.f, 0.f, 0.f);
      float4 w1 = make_float4(0.f, 0.f, 0.f, 0.f);
      if (k0 + wr < kend) {
        w0 = *(const float4*)(wp + wc);
        w1 = *(const float4*)(wp + 64 + wc);
      }
      *(float4*)&Ws[wr][wc]      = w0;
      *(float4*)&Ws[wr][64 + wc] = w1;
    }
    __syncthreads();
#pragma unroll
    for (int kk = 0; kk < 16; ++kk) {
      float4 a0 = *(const float4*)&As[kk][ty * 4];
      float4 a1 = *(const float4*)&As[kk][64 + ty * 4];
      float4 b0 = *(const float4*)&Ws[kk][tx * 4];
      float4 b1 = *(const float4*)&Ws[kk][64 + tx * 4];
      float av[8] = {a0.x, a0.y, a0.z, a0.w, a1.x, a1.y, a1.z, a1.w};
      float wv[8] = {b0.x, b0.y, b0.z, b0.w, b1.x, b1.y, b1.z, b1.w};
#pragma unroll
      for (int i = 0; i < 8; ++i)
#pragma unroll
        for (int j = 0; j < 8; ++j)
          acc[i][j] = fmaf(av[i], wv[j], acc[i][j]);
    }
    __syncthreads();
  }
  // split-K accumulate
#pragma unroll
  for (int i = 0; i < 8; ++i) {
    const int row = m0 + ((i < 4) ? (ty * 4 + i) : (64 + ty * 4 + (i - 4)));
    float* crow = C + (size_t)row * N + n0;
#pragma unroll
    for (int j = 0; j < 8; ++j) {
      const int col = (j < 4) ? (tx * 4 + j) : (64 + tx * 4 + (j - 4));
      atomicAdd(crow + col, acc[i][j]);
    }
  }
}

// ---------------------------------------------------------------------------
// In-place bias + LayerNorm + ReLU over rows of 1024. One block per row.
// Two-pass (mean, then centered variance) to track the numpy reference.
// ---------------------------------------------------------------------------
__global__ __launch_bounds__(256) void ln_relu_kernel(
    float* __restrict__ x, const float* __restrict__ bias,
    const float* __restrict__ g, const float* __restrict__ be)
{
  __shared__ float red[8];
  const int b = blockIdx.x, t = threadIdx.x;
  float* row = x + (size_t)b * HDIM;
  float4 v = *(float4*)(row + t * 4);
  const float4 bb = *(const float4*)(bias + t * 4);
  v.x += bb.x; v.y += bb.y; v.z += bb.z; v.w += bb.w;

  float s = (v.x + v.y) + (v.z + v.w);
#pragma unroll
  for (int o = 32; o; o >>= 1) s += __shfl_xor(s, o, 64);
  const int wid = t >> 6, lane = t & 63;
  if (lane == 0) red[wid] = s;
  __syncthreads();
  const float mean = (red[0] + red[1] + red[2] + red[3]) * (1.0f / HDIM);

  const float dx = v.x - mean, dy = v.y - mean, dz = v.z - mean, dw = v.w - mean;
  float s2 = (dx * dx + dy * dy) + (dz * dz + dw * dw);
#pragma unroll
  for (int o = 32; o; o >>= 1) s2 += __shfl_xor(s2, o, 64);
  if (lane == 0) red[4 + wid] = s2;
  __syncthreads();
  const float var = (red[4] + red[5] + red[6] + red[7]) * (1.0f / HDIM);
  const float inv = 1.0f / sqrtf(var + 1e-5f);

  const float4 gg = *(const float4*)(g + t * 4);
  const float4 ee = *(const float4*)(be + t * 4);
  float4 r;
  r.x = fmaxf(fmaf(dx * inv, gg.x, ee.x), 0.f);
  r.y = fmaxf(fmaf(dy * inv, gg.y, ee.y), 0.f);
  r.z = fmaxf(fmaf(dz * inv, gg.z, ee.z), 0.f);
  r.w = fmaxf(fmaf(dw * inv, gg.w, ee.w), 0.f);
  *(float4*)(row + t * 4) = r;
}

// ---------------------------------------------------------------------------
// Pack Wcat[1024][96]: cols 0..93 = Wp, col 94 = Wv, col 95 = 0
// ---------------------------------------------------------------------------
__global__ __launch_bounds__(256) void pack_wcat_kernel(
    const float* __restrict__ Wp, const float* __restrict__ Wv,
    float* __restrict__ Wc)
{
  const int i = blockIdx.x * 256 + threadIdx.x;   // 0..98303
  const int k = i / 96, c = i % 96;
  float v = 0.f;
  if (c < 94)       v = Wp[(size_t)k * 94 + c];
  else if (c == 94) v = Wv[k];
  Wc[i] = v;
}

// ---------------------------------------------------------------------------
// Head: out[r, 0..93] = x@Wp + bp, value[r] = x@Wv + bv.
// Block = 8 rows x 96 cols; 256 thr = 16 tx (6 cols) x 4 ty (2 rows) x 4 kz
// (K quarters). X row-tile staged fully in LDS; Wc streamed from L1/L2.
// ---------------------------------------------------------------------------
__global__ __launch_bounds__(256) void head_kernel(
    const float* __restrict__ X, const float* __restrict__ Wc,
    const float* __restrict__ bp, const float* __restrict__ bv,
    float* __restrict__ out)
{
  __shared__ float Xs[8][1025];
  __shared__ float red[4][8][96];
  const int t  = threadIdx.x;
  const int r0 = blockIdx.x * 8;
  const int tx = t & 15;
  const int ty = (t >> 4) & 3;
  const int kz = t >> 6;
  const int c0 = tx * 6;

  // stage 8 rows x 1024 (coalesced)
#pragma unroll 4
  for (int i = 0; i < 32; ++i) {
    const int e = i * 256 + t;
    Xs[e >> 10][e & 1023] = X[(size_t)(r0 + (e >> 10)) * HDIM + (e & 1023)];
  }
  __syncthreads();

  float acc[2][6] = {{0.f,0.f,0.f,0.f,0.f,0.f},{0.f,0.f,0.f,0.f,0.f,0.f}};
  const int kkend = kz * 256 + 256;
  for (int kk = kz * 256; kk < kkend; ++kk) {
    const float x0 = Xs[ty * 2][kk];
    const float x1 = Xs[ty * 2 + 1][kk];
    const float* wrow = Wc + (size_t)kk * 96 + c0;
    const float2 w01 = *(const float2*)(wrow);
    const float2 w23 = *(const float2*)(wrow + 2);
    const float2 w45 = *(const float2*)(wrow + 4);
    const float wv[6] = {w01.x, w01.y, w23.x, w23.y, w45.x, w45.y};
#pragma unroll
    for (int j = 0; j < 6; ++j) {
      acc[0][j] = fmaf(x0, wv[j], acc[0][j]);
      acc[1][j] = fmaf(x1, wv[j], acc[1][j]);
    }
  }
#pragma unroll
  for (int r = 0; r < 2; ++r)
#pragma unroll
    for (int j = 0; j < 6; ++j) red[kz][ty * 2 + r][c0 + j] = acc[r][j];
  __syncthreads();

  // 768 outputs, 3 per thread
#pragma unroll
  for (int q = 0; q < 3; ++q) {
    const int e = t * 3 + q;
    const int row = e / 96, c = e % 96;
    const float sum = red[0][row][c] + red[1][row][c] + red[2][row][c] + red[3][row][c];
    if (c < 94)       out[(size_t)(r0 + row) * NA2 + c] = sum + bp[c];
    else if (c == 94) out[VAL_OFF + r0 + row] = sum + bv[0];
  }
}

// ---------------------------------------------------------------------------
// Sampling: one wave per batch row. Masked argmax with gumbel (first-index
// tie-break, matching jnp.argmax), stable log_softmax gather, step-2 mask
// construction rules, writes logp/actions.
// ---------------------------------------------------------------------------
__global__ __launch_bounds__(64) void sample_kernel(
    const int* __restrict__ amask, const float* __restrict__ gum,
    float* __restrict__ out)
{
  const int b = blockIdx.x, lane = threadIdx.x;
  const bool valid = lane < NACT;
  const float* lrow = out + (size_t)b * NA2;

  const float lg1 = valid ? lrow[lane] : 0.f;
  const float lg2 = valid ? lrow[NACT + lane] : 0.f;
  const int   mk1 = valid ? amask[(size_t)b * NA2 + lane] : 0;
  const int   mk2 = valid ? amask[(size_t)b * NA2 + NACT + lane] : 0;
  const float gu1 = valid ? gum[(size_t)b * NA2 + lane] : 0.f;
  const float gu2 = valid ? gum[(size_t)b * NA2 + NACT + lane] : 0.f;

  // ---- step 1 ----
  const float l1 = valid ? ((mk1 == 0) ? NEGC : lg1) : -INFINITY;
  float key = valid ? (l1 + gu1) : -INFINITY;
  int idx = lane;
#pragma unroll
  for (int o = 32; o; o >>= 1) {
    const float ok = __shfl_xor(key, o, 64);
    const int   oi = __shfl_xor(idx, o, 64);
    if (ok > key || (ok == key && oi < idx)) { key = ok; idx = oi; }
  }
  const int a1 = idx;

  float mx = l1;
#pragma unroll
  for (int o = 32; o; o >>= 1) mx = fmaxf(mx, __shfl_xor(mx, o, 64));
  float ex = valid ? expf(l1 - mx) : 0.f;
#pragma unroll
  for (int o = 32; o; o >>= 1) ex += __shfl_xor(ex, o, 64);
  const float logp1 = __shfl(l1, a1, 64) - (mx + logf(ex));

  // ---- step 2 mask ----
  int m2 = mk2;
  if (a1 >= 1 && a1 <= 6 && lane == a1) m2 = 0;
  if (a1 > 26 && a1 <= 46 && lane >= 27 && valid) m2 = 0;
  if (a1 == 0 && lane == 0) m2 = 0;
  int tot = m2;
#pragma unroll
  for (int o = 32; o; o >>= 1) tot += __shfl_xor(tot, o, 64);
  if (a1 == 0 && tot == 0 && lane == 0) m2 = 1;

  const float l2 = valid ? ((m2 == 0) ? NEGC : lg2) : -INFINITY;
  float key2 = valid ? (l2 + gu2) : -INFINITY;
  int idx2 = lane;
#pragma unroll
  for (int o = 32; o; o >>= 1) {
    const float ok = __shfl_xor(key2, o, 64);
    const int   oi = __shfl_xor(idx2, o, 64);
    if (ok > key2 || (ok == key2 && oi < idx2)) { key2 = ok; idx2 = oi; }
  }
  const int a2 = idx2;

  float mx2 = l2;
#pragma unroll
  for (int o = 32; o; o >>= 1) mx2 = fmaxf(mx2, __shfl_xor(mx2, o, 64));
  float ex2 = valid ? expf(l2 - mx2) : 0.f;
#pragma unroll
  for (int o = 32; o; o >>= 1) ex2 += __shfl_xor(ex2, o, 64);
  const float logp2 = __shfl(l2, a2, 64) - (mx2 + logf(ex2));

  if (lane == 0) {
    out[LP_OFF  + b * 2]     = logp1;
    out[LP_OFF  + b * 2 + 1] = logp2;
    out[ACT_OFF + b * 2]     = (float)a1;
    out[ACT_OFF + b * 2 + 1] = (float)a2;
  }
}

// ---------------------------------------------------------------------------
extern "C" void kernel_launch(void* const* d_in, const int* in_sizes, int n_in,
                              void* d_out, int out_size, void* d_ws, size_t ws_size,
                              hipStream_t stream) {
  (void)in_sizes; (void)n_in; (void)out_size; (void)ws_size;
  const float* obs   = (const float*)d_in[0];
  const int*   amask = (const int*)  d_in[1];
  const float* gum   = (const float*)d_in[2];
  const float* W0    = (const float*)d_in[3];
  const float* b0    = (const float*)d_in[4];
  const float* g0    = (const float*)d_in[5];
  const float* be0   = (const float*)d_in[6];
  const float* W1    = (const float*)d_in[7];
  const float* b1    = (const float*)d_in[8];
  const float* g1    = (const float*)d_in[9];
  const float* be1   = (const float*)d_in[10];
  const float* W2    = (const float*)d_in[11];
  const float* b2    = (const float*)d_in[12];
  const float* g2    = (const float*)d_in[13];
  const float* be2   = (const float*)d_in[14];
  const float* Wp    = (const float*)d_in[15];
  const float* bp    = (const float*)d_in[16];
  const float* Wv    = (const float*)d_in[17];
  const float* bv    = (const float*)d_in[18];
  float* out = (float*)d_out;

  float* x0 = (float*)d_ws;                       // 4096*1024
  float* x1 = x0 + (size_t)BATCH * HDIM;          // 4096*1024
  float* wc = x1 + (size_t)BATCH * HDIM;          // 1024*96
  const size_t xbytes = (size_t)BATCH * HDIM * sizeof(float);

  pack_wcat_kernel<<<384, 256, 0, stream>>>(Wp, Wv, wc);

  // layer 0: x0 = obs @ W0 ; LN(+b0)+relu
  hipMemsetAsync(x0, 0, xbytes, stream);
  gemm_splitk_kernel<<<dim3(8, 32, 4), 256, 0, stream>>>(obs, W0, x0,
                                                         BATCH, HDIM, KDIM0, 1792);
  ln_relu_kernel<<<BATCH, 256, 0, stream>>>(x0, b0, g0, be0);

  // layer 1
  hipMemsetAsync(x1, 0, xbytes, stream);
  gemm_splitk_kernel<<<dim3(8, 32, 4), 256, 0, stream>>>(x0, W1, x1,
                                                         BATCH, HDIM, HDIM, 256);
  ln_relu_kernel<<<BATCH, 256, 0, stream>>>(x1, b1, g1, be1);

  // layer 2
  hipMemsetAsync(x0, 0, xbytes, stream);
  gemm_splitk_kernel<<<dim3(8, 32, 4), 256, 0, stream>>>(x1, W2, x0,
                                                         BATCH, HDIM, HDIM, 256);
  ln_relu_kernel<<<BATCH, 256, 0, stream>>>(x0, b2, g2, be2);

  // heads + sampling
  head_kernel<<<BATCH / 8, 256, 0, stream>>>(x0, wc, bp, bv, out);
  sample_kernel<<<BATCH, 64, 0, stream>>>(amask, gum, out);
}

// Round 2
// 650.756 us; speedup vs baseline: 2.7383x; 2.7383x over previous
//
#include <hip/hip_runtime.h>
#include <math.h>

#define BATCH 4096
#define HDIM  1024
#define KDIM0 7150
#define KP0   7168
#define NACT  47
#define NA2   94
#define NEGC  -1000000000.0f

// output layout (floats): logits [0,385024), logp [385024,393216),
// actions [393216,401408), value [401408,405504)
#define LP_OFF  385024
#define ACT_OFF 393216
#define VAL_OFF 401408

typedef _Float16 half8_t __attribute__((ext_vector_type(8)));
typedef _Float16 half4_t __attribute__((ext_vector_type(4)));
typedef _Float16 half2_t __attribute__((ext_vector_type(2)));
typedef float    float4_t __attribute__((ext_vector_type(4)));

// ---------------------------------------------------------------------------
// Weight convert: W[K][N] fp32 -> Wt_hi/Wt_lo f16 [N][Kp] (transposed, lo
// scaled by 4096 so it stays in f16 normal range; K padded with zeros).
// 64x64 tiles via LDS.
// ---------------------------------------------------------------------------
__global__ __launch_bounds__(256) void wconv_kernel(
    const float* __restrict__ W, _Float16* __restrict__ Wh,
    _Float16* __restrict__ Wl, int K, int N, int Kp)
{
  __shared__ float T[64][65];
  const int k0 = blockIdx.x * 64, n0 = blockIdx.y * 64, t = threadIdx.x;
#pragma unroll
  for (int p = 0; p < 16; ++p) {
    const int idx = p * 256 + t;
    const int r = idx >> 6, c = idx & 63;
    T[r][c] = (k0 + r < K) ? W[(size_t)(k0 + r) * N + n0 + c] : 0.f;
  }
  __syncthreads();
  const int n = t >> 2, kc = (t & 3) * 16;
#pragma unroll
  for (int e = 0; e < 16; ++e) {
    const float v = T[kc + e][n];
    const _Float16 h = (_Float16)v;
    const float r = v - (float)h;
    const _Float16 l = (_Float16)(r * 4096.f);
    const size_t o = (size_t)(n0 + n) * Kp + k0 + kc + e;
    Wh[o] = h; Wl[o] = l;
  }
}

// ---------------------------------------------------------------------------
// Activation decompose: A[M][K] fp32 -> Ah/Al f16 [M][Kp] (lo scaled 4096)
// ---------------------------------------------------------------------------
__global__ __launch_bounds__(256) void adecomp_kernel(
    const float* __restrict__ A, _Float16* __restrict__ Ah,
    _Float16* __restrict__ Al, int K, int Kp)
{
  const int m = blockIdx.y;
  const int k = blockIdx.x * 256 + threadIdx.x;
  const float v = (k < K) ? A[(size_t)m * K + k] : 0.f;
  const _Float16 h = (_Float16)v;
  const float r = v - (float)h;
  const _Float16 l = (_Float16)(r * 4096.f);
  const size_t o = (size_t)m * Kp + k;
  Ah[o] = h; Al[o] = l;
}

// ---------------------------------------------------------------------------
// f16x2 split MFMA GEMM: C[M][N] = A @ W, A given as hi/lo f16 planes
// [M][Kp], W as transposed hi/lo planes [N][Kp]. Block tile 128(M)x64(N),
// BK=64, 4 waves in 2x2, each wave 64x32 via 4x2 16x16x32 MFMA tiles.
// acc = hi*hi ; accx = hi*lo + lo*hi (scaled 2^12); D = acc + accx/4096.
// LDS chunks XOR-swizzled at 16B granularity -> <=2-way bank aliasing.
// ---------------------------------------------------------------------------
__global__ __launch_bounds__(256, 2) void gemm_f16x2_kernel(
    const _Float16* __restrict__ Ah, const _Float16* __restrict__ Al,
    const _Float16* __restrict__ Wh, const _Float16* __restrict__ Wl,
    float* __restrict__ C, int Kp, int N)
{
  __shared__ __align__(16) _Float16 As[2][128 * 64];
  __shared__ __align__(16) _Float16 Ws[2][64 * 64];
  const int t = threadIdx.x;
  const int n0 = blockIdx.x * 64;
  const int m0 = blockIdx.y * 128;
  const int lane = t & 63;
  const int wid = t >> 6;
  const int wm = (wid >> 1) * 64;
  const int wn = (wid & 1) * 32;
  const int l15 = lane & 15;
  const int quad = lane >> 4;

  const int sp = t >> 7;           // staging plane 0/1
  const int sr = (t & 127) >> 3;   // staging row within 16
  const int sc = t & 7;            // staging 16B chunk
  const _Float16* Ap = sp ? Al : Ah;
  const _Float16* Wp = sp ? Wl : Wh;

  float4_t acc[4][2], accx[4][2];
#pragma unroll
  for (int i = 0; i < 4; ++i)
#pragma unroll
    for (int j = 0; j < 2; ++j) {
      acc[i][j] = (float4_t){0.f, 0.f, 0.f, 0.f};
      accx[i][j] = (float4_t){0.f, 0.f, 0.f, 0.f};
    }

  for (int k0 = 0; k0 < Kp; k0 += 64) {
    // stage A: 2 planes x 128 rows x 64k, 16B chunks, swizzled
#pragma unroll
    for (int q = 0; q < 8; ++q) {
      const int m = q * 16 + sr;
      const float4_t v = *(const float4_t*)(Ap + (size_t)(m0 + m) * Kp + k0 + sc * 8);
      *(float4_t*)&As[sp][m * 64 + ((sc ^ (m & 7)) << 3)] = v;
    }
    // stage W: 2 planes x 64 rows x 64k
#pragma unroll
    for (int q = 0; q < 4; ++q) {
      const int n = q * 16 + sr;
      const float4_t v = *(const float4_t*)(Wp + (size_t)(n0 + n) * Kp + k0 + sc * 8);
      *(float4_t*)&Ws[sp][n * 64 + ((sc ^ (n & 7)) << 3)] = v;
    }
    __syncthreads();
#pragma unroll
    for (int ks = 0; ks < 2; ++ks) {
      half8_t ah[4], al[4], wh[2], wl[2];
#pragma unroll
      for (int i = 0; i < 4; ++i) {
        const int row = wm + i * 16 + l15;
        const int o = row * 64 + ((((ks << 2) + quad) ^ (row & 7)) << 3);
        ah[i] = *(const half8_t*)&As[0][o];
        al[i] = *(const half8_t*)&As[1][o];
      }
#pragma unroll
      for (int j = 0; j < 2; ++j) {
        const int rn = wn + j * 16 + l15;
        const int o = rn * 64 + ((((ks << 2) + quad) ^ (rn & 7)) << 3);
        wh[j] = *(const half8_t*)&Ws[0][o];
        wl[j] = *(const half8_t*)&Ws[1][o];
      }
#pragma unroll
      for (int i = 0; i < 4; ++i)
#pragma unroll
        for (int j = 0; j < 2; ++j) {
          acc[i][j]  = __builtin_amdgcn_mfma_f32_16x16x32_f16(ah[i], wh[j], acc[i][j], 0, 0, 0);
          accx[i][j] = __builtin_amdgcn_mfma_f32_16x16x32_f16(ah[i], wl[j], accx[i][j], 0, 0, 0);
          accx[i][j] = __builtin_amdgcn_mfma_f32_16x16x32_f16(al[i], wh[j], accx[i][j], 0, 0, 0);
        }
    }
    __syncthreads();
  }
  const float s = 1.0f / 4096.0f;
#pragma unroll
  for (int i = 0; i < 4; ++i)
#pragma unroll
    for (int j = 0; j < 2; ++j) {
      const int col = n0 + wn + j * 16 + l15;
#pragma unroll
      for (int r = 0; r < 4; ++r) {
        const int row = m0 + wm + i * 16 + quad * 4 + r;
        C[(size_t)row * N + col] = acc[i][j][r] + accx[i][j][r] * s;
      }
    }
}

// ---------------------------------------------------------------------------
// Same GEMM but A is fp32 [M][K] decomposed in-kernel during staging
// (fallback when ws can't hold obs planes). K guarded on last chunk.
// ---------------------------------------------------------------------------
__global__ __launch_bounds__(256, 2) void gemm_f16x2_a32_kernel(
    const float* __restrict__ A,
    const _Float16* __restrict__ Wh, const _Float16* __restrict__ Wl,
    float* __restrict__ C, int K, int Kp, int N)
{
  __shared__ __align__(16) _Float16 As[2][128 * 64];
  __shared__ __align__(16) _Float16 Ws[2][64 * 64];
  const int t = threadIdx.x;
  const int n0 = blockIdx.x * 64;
  const int m0 = blockIdx.y * 128;
  const int lane = t & 63;
  const int wid = t >> 6;
  const int wm = (wid >> 1) * 64;
  const int wn = (wid & 1) * 32;
  const int l15 = lane & 15;
  const int quad = lane >> 4;

  const int sp = t >> 7;
  const int sr = (t & 127) >> 3;
  const int sc = t & 7;
  const _Float16* Wp = sp ? Wl : Wh;

  const int a_k2 = (t & 31) * 2;   // k offset (float2)
  const int a_mr = t >> 5;         // row within 8

  float4_t acc[4][2], accx[4][2];
#pragma unroll
  for (int i = 0; i < 4; ++i)
#pragma unroll
    for (int j = 0; j < 2; ++j) {
      acc[i][j] = (float4_t){0.f, 0.f, 0.f, 0.f};
      accx[i][j] = (float4_t){0.f, 0.f, 0.f, 0.f};
    }

  for (int k0 = 0; k0 < Kp; k0 += 64) {
    const int aoff = ((a_k2 >> 3) << 3) /*chunk*8*/;
    if (k0 + 64 <= K) {
#pragma unroll
      for (int q = 0; q < 16; ++q) {
        const int m = q * 8 + a_mr;
        const float2 v = *(const float2*)(A + (size_t)(m0 + m) * K + k0 + a_k2);
        const _Float16 h0 = (_Float16)v.x; const float r0 = v.x - (float)h0;
        const _Float16 h1 = (_Float16)v.y; const float r1 = v.y - (float)h1;
        const half2_t hh = {h0, h1};
        const half2_t ll = {(_Float16)(r0 * 4096.f), (_Float16)(r1 * 4096.f)};
        const int o = m * 64 + (((a_k2 >> 3) ^ (m & 7)) << 3) + (a_k2 & 7);
        *(half2_t*)&As[0][o] = hh;
        *(half2_t*)&As[1][o] = ll;
      }
    } else {
#pragma unroll
      for (int q = 0; q < 16; ++q) {
        const int m = q * 8 + a_mr;
        const float x0 = (k0 + a_k2 < K) ? A[(size_t)(m0 + m) * K + k0 + a_k2] : 0.f;
        const float x1 = (k0 + a_k2 + 1 < K) ? A[(size_t)(m0 + m) * K + k0 + a_k2 + 1] : 0.f;
        const _Float16 h0 = (_Float16)x0; const float r0 = x0 - (float)h0;
        const _Float16 h1 = (_Float16)x1; const float r1 = x1 - (float)h1;
        const half2_t hh = {h0, h1};
        const half2_t ll = {(_Float16)(r0 * 4096.f), (_Float16)(r1 * 4096.f)};
        const int o = m * 64 + (((a_k2 >> 3) ^ (m & 7)) << 3) + (a_k2 & 7);
        *(half2_t*)&As[0][o] = hh;
        *(half2_t*)&As[1][o] = ll;
      }
    }
    (void)aoff;
#pragma unroll
    for (int q = 0; q < 4; ++q) {
      const int n = q * 16 + sr;
      const float4_t v = *(const float4_t*)(Wp + (size_t)(n0 + n) * Kp + k0 + sc * 8);
      *(float4_t*)&Ws[sp][n * 64 + ((sc ^ (n & 7)) << 3)] = v;
    }
    __syncthreads();
#pragma unroll
    for (int ks = 0; ks < 2; ++ks) {
      half8_t ah[4], al[4], wh[2], wl[2];
#pragma unroll
      for (int i = 0; i < 4; ++i) {
        const int row = wm + i * 16 + l15;
        const int o = row * 64 + ((((ks << 2) + quad) ^ (row & 7)) << 3);
        ah[i] = *(const half8_t*)&As[0][o];
        al[i] = *(const half8_t*)&As[1][o];
      }
#pragma unroll
      for (int j = 0; j < 2; ++j) {
        const int rn = wn + j * 16 + l15;
        const int o = rn * 64 + ((((ks << 2) + quad) ^ (rn & 7)) << 3);
        wh[j] = *(const half8_t*)&Ws[0][o];
        wl[j] = *(const half8_t*)&Ws[1][o];
      }
#pragma unroll
      for (int i = 0; i < 4; ++i)
#pragma unroll
        for (int j = 0; j < 2; ++j) {
          acc[i][j]  = __builtin_amdgcn_mfma_f32_16x16x32_f16(ah[i], wh[j], acc[i][j], 0, 0, 0);
          accx[i][j] = __builtin_amdgcn_mfma_f32_16x16x32_f16(ah[i], wl[j], accx[i][j], 0, 0, 0);
          accx[i][j] = __builtin_amdgcn_mfma_f32_16x16x32_f16(al[i], wh[j], accx[i][j], 0, 0, 0);
        }
    }
    __syncthreads();
  }
  const float s = 1.0f / 4096.0f;
#pragma unroll
  for (int i = 0; i < 4; ++i)
#pragma unroll
    for (int j = 0; j < 2; ++j) {
      const int col = n0 + wn + j * 16 + l15;
#pragma unroll
      for (int r = 0; r < 4; ++r) {
        const int row = m0 + wm + i * 16 + quad * 4 + r;
        C[(size_t)row * N + col] = acc[i][j][r] + accx[i][j][r] * s;
      }
    }
}

// ---------------------------------------------------------------------------
// bias + LayerNorm + ReLU, output as f16 hi/lo planes (next GEMM's A input)
// ---------------------------------------------------------------------------
__global__ __launch_bounds__(256) void ln_relu_f16_kernel(
    const float* __restrict__ x, const float* __restrict__ bias,
    const float* __restrict__ g, const float* __restrict__ be,
    _Float16* __restrict__ oh, _Float16* __restrict__ ol)
{
  __shared__ float red[8];
  const int b = blockIdx.x, t = threadIdx.x;
  const float* row = x + (size_t)b * HDIM;
  float4 v = *(const float4*)(row + t * 4);
  const float4 bb = *(const float4*)(bias + t * 4);
  v.x += bb.x; v.y += bb.y; v.z += bb.z; v.w += bb.w;

  float s = (v.x + v.y) + (v.z + v.w);
#pragma unroll
  for (int o = 32; o; o >>= 1) s += __shfl_xor(s, o, 64);
  const int wid = t >> 6, lane = t & 63;
  if (lane == 0) red[wid] = s;
  __syncthreads();
  const float mean = (red[0] + red[1] + red[2] + red[3]) * (1.0f / HDIM);

  const float dx = v.x - mean, dy = v.y - mean, dz = v.z - mean, dw = v.w - mean;
  float s2 = (dx * dx + dy * dy) + (dz * dz + dw * dw);
#pragma unroll
  for (int o = 32; o; o >>= 1) s2 += __shfl_xor(s2, o, 64);
  if (lane == 0) red[4 + wid] = s2;
  __syncthreads();
  const float var = (red[4] + red[5] + red[6] + red[7]) * (1.0f / HDIM);
  const float inv = 1.0f / sqrtf(var + 1e-5f);

  const float4 gg = *(const float4*)(g + t * 4);
  const float4 ee = *(const float4*)(be + t * 4);
  float r0 = fmaxf(fmaf(dx * inv, gg.x, ee.x), 0.f);
  float r1 = fmaxf(fmaf(dy * inv, gg.y, ee.y), 0.f);
  float r2 = fmaxf(fmaf(dz * inv, gg.z, ee.z), 0.f);
  float r3 = fmaxf(fmaf(dw * inv, gg.w, ee.w), 0.f);
  const _Float16 h0 = (_Float16)r0, h1 = (_Float16)r1, h2 = (_Float16)r2, h3 = (_Float16)r3;
  const half4_t hv = {h0, h1, h2, h3};
  const half4_t lv = {(_Float16)((r0 - (float)h0) * 4096.f),
                      (_Float16)((r1 - (float)h1) * 4096.f),
                      (_Float16)((r2 - (float)h2) * 4096.f),
                      (_Float16)((r3 - (float)h3) * 4096.f)};
  *(half4_t*)(oh + (size_t)b * HDIM + t * 4) = hv;
  *(half4_t*)(ol + (size_t)b * HDIM + t * 4) = lv;
}

// ---------------------------------------------------------------------------
// bias + LayerNorm + ReLU in-place fp32 (final layer; head reads fp32)
// ---------------------------------------------------------------------------
__global__ __launch_bounds__(256) void ln_relu_kernel(
    float* __restrict__ x, const float* __restrict__ bias,
    const float* __restrict__ g, const float* __restrict__ be)
{
  __shared__ float red[8];
  const int b = blockIdx.x, t = threadIdx.x;
  float* row = x + (size_t)b * HDIM;
  float4 v = *(float4*)(row + t * 4);
  const float4 bb = *(const float4*)(bias + t * 4);
  v.x += bb.x; v.y += bb.y; v.z += bb.z; v.w += bb.w;

  float s = (v.x + v.y) + (v.z + v.w);
#pragma unroll
  for (int o = 32; o; o >>= 1) s += __shfl_xor(s, o, 64);
  const int wid = t >> 6, lane = t & 63;
  if (lane == 0) red[wid] = s;
  __syncthreads();
  const float mean = (red[0] + red[1] + red[2] + red[3]) * (1.0f / HDIM);

  const float dx = v.x - mean, dy = v.y - mean, dz = v.z - mean, dw = v.w - mean;
  float s2 = (dx * dx + dy * dy) + (dz * dz + dw * dw);
#pragma unroll
  for (int o = 32; o; o >>= 1) s2 += __shfl_xor(s2, o, 64);
  if (lane == 0) red[4 + wid] = s2;
  __syncthreads();
  const float var = (red[4] + red[5] + red[6] + red[7]) * (1.0f / HDIM);
  const float inv = 1.0f / sqrtf(var + 1e-5f);

  const float4 gg = *(const float4*)(g + t * 4);
  const float4 ee = *(const float4*)(be + t * 4);
  float4 r;
  r.x = fmaxf(fmaf(dx * inv, gg.x, ee.x), 0.f);
  r.y = fmaxf(fmaf(dy * inv, gg.y, ee.y), 0.f);
  r.z = fmaxf(fmaf(dz * inv, gg.z, ee.z), 0.f);
  r.w = fmaxf(fmaf(dw * inv, gg.w, ee.w), 0.f);
  *(float4*)(row + t * 4) = r;
}

// ---------------------------------------------------------------------------
// Pack Wcat[1024][96]: cols 0..93 = Wp, col 94 = Wv, col 95 = 0
// ---------------------------------------------------------------------------
__global__ __launch_bounds__(256) void pack_wcat_kernel(
    const float* __restrict__ Wp, const float* __restrict__ Wv,
    float* __restrict__ Wc)
{
  const int i = blockIdx.x * 256 + threadIdx.x;
  const int k = i / 96, c = i % 96;
  float v = 0.f;
  if (c < 94)       v = Wp[(size_t)k * 94 + c];
  else if (c == 94) v = Wv[k];
  Wc[i] = v;
}

// ---------------------------------------------------------------------------
// Head: out[r, 0..93] = x@Wp + bp, value[r] = x@Wv + bv. fp32 VALU.
// ---------------------------------------------------------------------------
__global__ __launch_bounds__(256) void head_kernel(
    const float* __restrict__ X, const float* __restrict__ Wc,
    const float* __restrict__ bp, const float* __restrict__ bv,
    float* __restrict__ out)
{
  __shared__ float Xs[8][1025];
  __shared__ float red[4][8][96];
  const int t  = threadIdx.x;
  const int r0 = blockIdx.x * 8;
  const int tx = t & 15;
  const int ty = (t >> 4) & 3;
  const int kz = t >> 6;
  const int c0 = tx * 6;

#pragma unroll 4
  for (int i = 0; i < 32; ++i) {
    const int e = i * 256 + t;
    Xs[e >> 10][e & 1023] = X[(size_t)(r0 + (e >> 10)) * HDIM + (e & 1023)];
  }
  __syncthreads();

  float acc[2][6] = {{0.f,0.f,0.f,0.f,0.f,0.f},{0.f,0.f,0.f,0.f,0.f,0.f}};
  const int kkend = kz * 256 + 256;
  for (int kk = kz * 256; kk < kkend; ++kk) {
    const float x0 = Xs[ty * 2][kk];
    const float x1 = Xs[ty * 2 + 1][kk];
    const float* wrow = Wc + (size_t)kk * 96 + c0;
    const float2 w01 = *(const float2*)(wrow);
    const float2 w23 = *(const float2*)(wrow + 2);
    const float2 w45 = *(const float2*)(wrow + 4);
    const float wv[6] = {w01.x, w01.y, w23.x, w23.y, w45.x, w45.y};
#pragma unroll
    for (int j = 0; j < 6; ++j) {
      acc[0][j] = fmaf(x0, wv[j], acc[0][j]);
      acc[1][j] = fmaf(x1, wv[j], acc[1][j]);
    }
  }
#pragma unroll
  for (int r = 0; r < 2; ++r)
#pragma unroll
    for (int j = 0; j < 6; ++j) red[kz][ty * 2 + r][c0 + j] = acc[r][j];
  __syncthreads();

#pragma unroll
  for (int q = 0; q < 3; ++q) {
    const int e = t * 3 + q;
    const int row = e / 96, c = e % 96;
    const float sum = red[0][row][c] + red[1][row][c] + red[2][row][c] + red[3][row][c];
    if (c < 94)       out[(size_t)(r0 + row) * NA2 + c] = sum + bp[c];
    else if (c == 94) out[VAL_OFF + r0 + row] = sum + bv[0];
  }
}

// ---------------------------------------------------------------------------
// Sampling: one wave per batch row (unchanged from passing R1 version).
// ---------------------------------------------------------------------------
__global__ __launch_bounds__(64) void sample_kernel(
    const int* __restrict__ amask, const float* __restrict__ gum,
    float* __restrict__ out)
{
  const int b = blockIdx.x, lane = threadIdx.x;
  const bool valid = lane < NACT;
  const float* lrow = out + (size_t)b * NA2;

  const float lg1 = valid ? lrow[lane] : 0.f;
  const float lg2 = valid ? lrow[NACT + lane] : 0.f;
  const int   mk1 = valid ? amask[(size_t)b * NA2 + lane] : 0;
  const int   mk2 = valid ? amask[(size_t)b * NA2 + NACT + lane] : 0;
  const float gu1 = valid ? gum[(size_t)b * NA2 + lane] : 0.f;
  const float gu2 = valid ? gum[(size_t)b * NA2 + NACT + lane] : 0.f;

  const float l1 = valid ? ((mk1 == 0) ? NEGC : lg1) : -INFINITY;
  float key = valid ? (l1 + gu1) : -INFINITY;
  int idx = lane;
#pragma unroll
  for (int o = 32; o; o >>= 1) {
    const float ok = __shfl_xor(key, o, 64);
    const int   oi = __shfl_xor(idx, o, 64);
    if (ok > key || (ok == key && oi < idx)) { key = ok; idx = oi; }
  }
  const int a1 = idx;

  float mx = l1;
#pragma unroll
  for (int o = 32; o; o >>= 1) mx = fmaxf(mx, __shfl_xor(mx, o, 64));
  float ex = valid ? expf(l1 - mx) : 0.f;
#pragma unroll
  for (int o = 32; o; o >>= 1) ex += __shfl_xor(ex, o, 64);
  const float logp1 = __shfl(l1, a1, 64) - (mx + logf(ex));

  int m2 = mk2;
  if (a1 >= 1 && a1 <= 6 && lane == a1) m2 = 0;
  if (a1 > 26 && a1 <= 46 && lane >= 27 && valid) m2 = 0;
  if (a1 == 0 && lane == 0) m2 = 0;
  int tot = m2;
#pragma unroll
  for (int o = 32; o; o >>= 1) tot += __shfl_xor(tot, o, 64);
  if (a1 == 0 && tot == 0 && lane == 0) m2 = 1;

  const float l2 = valid ? ((m2 == 0) ? NEGC : lg2) : -INFINITY;
  float key2 = valid ? (l2 + gu2) : -INFINITY;
  int idx2 = lane;
#pragma unroll
  for (int o = 32; o; o >>= 1) {
    const float ok = __shfl_xor(key2, o, 64);
    const int   oi = __shfl_xor(idx2, o, 64);
    if (ok > key2 || (ok == key2 && oi < idx2)) { key2 = ok; idx2 = oi; }
  }
  const int a2 = idx2;

  float mx2 = l2;
#pragma unroll
  for (int o = 32; o; o >>= 1) mx2 = fmaxf(mx2, __shfl_xor(mx2, o, 64));
  float ex2 = valid ? expf(l2 - mx2) : 0.f;
#pragma unroll
  for (int o = 32; o; o >>= 1) ex2 += __shfl_xor(ex2, o, 64);
  const float logp2 = __shfl(l2, a2, 64) - (mx2 + logf(ex2));

  if (lane == 0) {
    out[LP_OFF  + b * 2]     = logp1;
    out[LP_OFF  + b * 2 + 1] = logp2;
    out[ACT_OFF + b * 2]     = (float)a1;
    out[ACT_OFF + b * 2 + 1] = (float)a2;
  }
}

// ---------------------------------------------------------------------------
extern "C" void kernel_launch(void* const* d_in, const int* in_sizes, int n_in,
                              void* d_out, int out_size, void* d_ws, size_t ws_size,
                              hipStream_t stream) {
  (void)in_sizes; (void)n_in; (void)out_size;
  const float* obs   = (const float*)d_in[0];
  const int*   amask = (const int*)  d_in[1];
  const float* gum   = (const float*)d_in[2];
  const float* W0    = (const float*)d_in[3];
  const float* b0    = (const float*)d_in[4];
  const float* g0    = (const float*)d_in[5];
  const float* be0   = (const float*)d_in[6];
  const float* W1    = (const float*)d_in[7];
  const float* b1    = (const float*)d_in[8];
  const float* g1    = (const float*)d_in[9];
  const float* be1   = (const float*)d_in[10];
  const float* W2    = (const float*)d_in[11];
  const float* b2    = (const float*)d_in[12];
  const float* g2    = (const float*)d_in[13];
  const float* be2   = (const float*)d_in[14];
  const float* Wp    = (const float*)d_in[15];
  const float* bp    = (const float*)d_in[16];
  const float* Wv    = (const float*)d_in[17];
  const float* bv    = (const float*)d_in[18];
  float* out = (float*)d_out;

  char* ws = (char*)d_ws;
  size_t off = 0;
  auto take = [&](size_t n) { char* p = ws + off; off += (n + 255) & ~(size_t)255; return p; };
  _Float16* wt0h = (_Float16*)take((size_t)HDIM * KP0 * 2);
  _Float16* wt0l = (_Float16*)take((size_t)HDIM * KP0 * 2);
  _Float16* wt1h = (_Float16*)take((size_t)HDIM * HDIM * 2);
  _Float16* wt1l = (_Float16*)take((size_t)HDIM * HDIM * 2);
  _Float16* wt2h = (_Float16*)take((size_t)HDIM * HDIM * 2);
  _Float16* wt2l = (_Float16*)take((size_t)HDIM * HDIM * 2);
  float*    xf   = (float*)   take((size_t)BATCH * HDIM * 4);
  float*    wc   = (float*)   take((size_t)HDIM * 96 * 4);
  _Float16* oph  = (_Float16*)take((size_t)BATCH * KP0 * 2);
  _Float16* opl  = (_Float16*)take((size_t)BATCH * KP0 * 2);
  const bool big = (off <= ws_size);

  // weight conversions (transpose + f16x2 decompose)
  wconv_kernel<<<dim3(KP0 / 64, HDIM / 64), 256, 0, stream>>>(W0, wt0h, wt0l, KDIM0, HDIM, KP0);
  wconv_kernel<<<dim3(16, 16), 256, 0, stream>>>(W1, wt1h, wt1l, HDIM, HDIM, HDIM);
  wconv_kernel<<<dim3(16, 16), 256, 0, stream>>>(W2, wt2h, wt2l, HDIM, HDIM, HDIM);
  pack_wcat_kernel<<<384, 256, 0, stream>>>(Wp, Wv, wc);

  // layer 0
  if (big) {
    adecomp_kernel<<<dim3(KP0 / 256, BATCH), 256, 0, stream>>>(obs, oph, opl, KDIM0, KP0);
    gemm_f16x2_kernel<<<dim3(HDIM / 64, BATCH / 128), 256, 0, stream>>>(
        oph, opl, wt0h, wt0l, xf, KP0, HDIM);
  } else {
    gemm_f16x2_a32_kernel<<<dim3(HDIM / 64, BATCH / 128), 256, 0, stream>>>(
        obs, wt0h, wt0l, xf, KDIM0, KP0, HDIM);
  }
  // reuse oph/opl-independent plane buffers for activations: use wt-sized? No:
  // activations planes go into dedicated buffers below (aliasing oph region
  // is safe in big path only after gemm0 consumed it; keep separate).
  _Float16* xph = big ? oph : (_Float16*)take(0);  // placeholder, set below
  _Float16* xpl;
  if (big) {
    // reuse the obs-plane buffers (no longer needed after GEMM0)
    xph = oph; xpl = opl;
  } else {
    xph = (_Float16*)take((size_t)BATCH * HDIM * 2);
    xpl = (_Float16*)take((size_t)BATCH * HDIM * 2);
  }
  ln_relu_f16_kernel<<<BATCH, 256, 0, stream>>>(xf, b0, g0, be0, xph, xpl);

  // layer 1
  gemm_f16x2_kernel<<<dim3(HDIM / 64, BATCH / 128), 256, 0, stream>>>(
      xph, xpl, wt1h, wt1l, xf, HDIM, HDIM);
  ln_relu_f16_kernel<<<BATCH, 256, 0, stream>>>(xf, b1, g1, be1, xph, xpl);

  // layer 2
  gemm_f16x2_kernel<<<dim3(HDIM / 64, BATCH / 128), 256, 0, stream>>>(
      xph, xpl, wt2h, wt2l, xf, HDIM, HDIM);
  ln_relu_kernel<<<BATCH, 256, 0, stream>>>(xf, b2, g2, be2);

  // heads + sampling
  head_kernel<<<BATCH / 8, 256, 0, stream>>>(xf, wc, bp, bv, out);
  sample_kernel<<<BATCH, 64, 0, stream>>>(amask, gum, out);
}